// Round 1
// baseline (461.888 us; speedup 1.0000x reference)
//
#include <hip/hip_runtime.h>

#define NEGINF (-__builtin_inff())

__device__ __forceinline__ bool precedes(float si, int ni, float sj, int nj) {
    // total order: score descending, then original index ascending
    return (si > sj) || (si == sj && ni < nj);
}

__device__ __forceinline__ float4 decode_box(const float* __restrict__ br4,
                                             float rx1, float ry1, float rx2, float ry2,
                                             float wmax, float hmax) {
    const float CLIP = 4.135166556742356f;  // log(1000/16)
    float w  = rx2 - rx1 + 1.0f;
    float h  = ry2 - ry1 + 1.0f;
    float cx = rx1 + 0.5f * w;
    float cy = ry1 + 0.5f * h;
    float dx = br4[0] / 10.0f;
    float dy = br4[1] / 10.0f;
    float dw = fminf(br4[2] / 5.0f, CLIP);
    float dh = fminf(br4[3] / 5.0f, CLIP);
    float pcx = dx * w + cx;
    float pcy = dy * h + cy;
    float pw  = expf(dw) * w;
    float ph  = expf(dh) * h;
    float4 b;
    b.x = fminf(fmaxf(pcx - 0.5f * pw, 0.0f), wmax);
    b.y = fminf(fmaxf(pcy - 0.5f * ph, 0.0f), hmax);
    b.z = fminf(fmaxf(pcx + 0.5f * pw - 1.0f, 0.0f), wmax);
    b.w = fminf(fmaxf(pcy + 0.5f * ph - 1.0f, 0.0f), hmax);
    return b;
}

// ---------------- k0: zero counters ----------------
__global__ void k0_init(int* cnt, int* pool_cnt, int K) {
    int t = threadIdx.x;
    if (t < K) cnt[t] = 0;
    if (t == K) *pool_cnt = 0;
}

// ---------------- k1: softmax + threshold + append candidates ----------------
__global__ void k1_softmax(const float* __restrict__ logits, int C,
                           int* __restrict__ cnt,
                           float* __restrict__ cand_s, int* __restrict__ cand_n,
                           int slots) {
    int n = blockIdx.x;
    int lane = threadIdx.x;  // 64 threads = 1 wave
    const float* row = logits + (size_t)n * C;

    float l0 = (lane < C) ? row[lane] : NEGINF;
    float l1 = (lane + 64 < C) ? row[lane + 64] : NEGINF;

    float m = fmaxf(l0, l1);
    #pragma unroll
    for (int o = 32; o; o >>= 1) m = fmaxf(m, __shfl_xor(m, o));

    float e0 = (lane < C) ? expf(l0 - m) : 0.0f;
    float e1 = (lane + 64 < C) ? expf(l1 - m) : 0.0f;
    float s = e0 + e1;
    #pragma unroll
    for (int o = 32; o; o >>= 1) s += __shfl_xor(s, o);

    // class c = lane (skip background 0) and c = lane+64
    if (lane >= 1 && lane < C) {
        float p = e0 / s;
        if (p > 0.05f) {
            int k = lane - 1;
            int slot = atomicAdd(&cnt[k], 1);
            if (slot < slots) {
                cand_s[(size_t)k * slots + slot] = p;
                cand_n[(size_t)k * slots + slot] = n;
            }
        }
    }
    if (lane + 64 < C) {
        float p = e1 / s;
        if (p > 0.05f) {
            int k = lane + 64 - 1;
            int slot = atomicAdd(&cnt[k], 1);
            if (slot < slots) {
                cand_s[(size_t)k * slots + slot] = p;
                cand_n[(size_t)k * slots + slot] = n;
            }
        }
    }
}

// ---------------- k2: per-class decode + sort + greedy NMS + pool append ----------------
#define SORT_N 1024

__global__ void k2_sort_nms(const float* __restrict__ boxreg, const float* __restrict__ refb,
                            const int* __restrict__ Hp, const int* __restrict__ Wp, int C,
                            const int* __restrict__ cnt,
                            const float* __restrict__ cand_s, const int* __restrict__ cand_n,
                            int slots,
                            int* __restrict__ pool_cnt, float* __restrict__ pool_s,
                            int* __restrict__ pool_rank, float* __restrict__ pool_box,
                            int poolcap) {
    __shared__ float s_l[SORT_N];
    __shared__ int   n_l[SORT_N];
    __shared__ float4 b_l[SORT_N];
    __shared__ unsigned char keepf[SORT_N];

    int k = blockIdx.x;      // 0..K-1
    int c = k + 1;           // class id
    int tid = threadIdx.x;   // 256 threads
    int M = cnt[k];
    if (M > slots) M = slots;
    if (M == 0) return;

    float wmax = (float)(*Wp) - 1.0f;
    float hmax = (float)(*Hp) - 1.0f;

    // load + decode
    for (int i = tid; i < SORT_N; i += 256) {
        if (i < M) {
            float sc = cand_s[(size_t)k * slots + i];
            int n = cand_n[(size_t)k * slots + i];
            const float* rb = refb + (size_t)n * 4;
            const float* br = boxreg + (size_t)n * (4 * C) + (size_t)c * 4;
            b_l[i] = decode_box(br, rb[0], rb[1], rb[2], rb[3], wmax, hmax);
            s_l[i] = sc;
            n_l[i] = n;
        } else {
            s_l[i] = NEGINF;
            n_l[i] = 0x7fffffff;
            b_l[i] = make_float4(0.f, 0.f, 0.f, 0.f);
        }
    }

    // bitonic sort, ascending by "precedes" == descending by score (ties: n asc)
    for (int size = 2; size <= SORT_N; size <<= 1) {
        for (int stride = size >> 1; stride > 0; stride >>= 1) {
            __syncthreads();
            for (int i = tid; i < SORT_N; i += 256) {
                int j = i ^ stride;
                if (j > i) {
                    bool up = ((i & size) == 0);
                    float si = s_l[i], sj = s_l[j];
                    int ni = n_l[i], nj = n_l[j];
                    bool do_swap = up ? precedes(sj, nj, si, ni)
                                      : precedes(si, ni, sj, nj);
                    if (do_swap) {
                        s_l[i] = sj; s_l[j] = si;
                        n_l[i] = nj; n_l[j] = ni;
                        float4 t = b_l[i]; b_l[i] = b_l[j]; b_l[j] = t;
                    }
                }
            }
        }
    }
    __syncthreads();

    for (int i = tid; i < SORT_N; i += 256) keepf[i] = (i < M) ? 1 : 0;

    // greedy NMS (IoU with +1 convention, strict > 0.5)
    for (int i = 0; i < M; ++i) {
        __syncthreads();
        if (!keepf[i]) continue;  // uniform: all threads read same LDS byte
        float4 bi = b_l[i];
        float ai = (bi.z - bi.x + 1.0f) * (bi.w - bi.y + 1.0f);
        for (int j = i + 1 + tid; j < M; j += 256) {
            if (!keepf[j]) continue;
            float4 bj = b_l[j];
            float iw = fminf(bi.z, bj.z) - fmaxf(bi.x, bj.x) + 1.0f;
            if (iw <= 0.0f) continue;
            float ih = fminf(bi.w, bj.w) - fmaxf(bi.y, bj.y) + 1.0f;
            if (ih <= 0.0f) continue;
            float inter = iw * ih;
            float aj = (bj.z - bj.x + 1.0f) * (bj.w - bj.y + 1.0f);
            float iou = inter / (ai + aj - inter);
            if (iou > 0.5f) keepf[j] = 0;
        }
    }
    __syncthreads();

    // append survivors to global pool
    for (int i = tid; i < M; i += 256) {
        if (keepf[i]) {
            int p = atomicAdd(pool_cnt, 1);
            if (p < poolcap) {
                pool_s[p] = s_l[i];
                pool_rank[p] = k * 1024 + i;  // matches reference flat index k*N + sorted_pos
                float4 b = b_l[i];
                pool_box[(size_t)p * 4 + 0] = b.x;
                pool_box[(size_t)p * 4 + 1] = b.y;
                pool_box[(size_t)p * 4 + 2] = b.z;
                pool_box[(size_t)p * 4 + 3] = b.w;
            }
        }
    }
}

// ---------------- k3: global top-100 + output write ----------------
#define SEL_CAP 8192
#define DETS 100

__global__ void k3_topk(const int* __restrict__ pool_cnt, float* __restrict__ pool_s,
                        const int* __restrict__ pool_rank, const float* __restrict__ pool_box,
                        int poolcap, float* __restrict__ out) {
    __shared__ float ls[SEL_CAP];
    __shared__ int   lr[SEL_CAP];
    __shared__ float rs[256];
    __shared__ int   rr[256];
    __shared__ int   ri[256];

    int tid = threadIdx.x;  // 256 threads
    int P = *pool_cnt;
    if (P > poolcap) P = poolcap;
    bool use_lds = (P <= SEL_CAP);

    if (use_lds) {
        for (int i = tid; i < P; i += 256) { ls[i] = pool_s[i]; lr[i] = pool_rank[i]; }
    }
    __syncthreads();

    for (int it = 0; it < DETS; ++it) {
        float bs = NEGINF; int br = 0x7fffffff; int bi = -1;
        for (int i = tid; i < P; i += 256) {
            float s = use_lds ? ls[i] : pool_s[i];
            int r = use_lds ? lr[i] : pool_rank[i];
            if (s > bs || (s == bs && r < br)) { bs = s; br = r; bi = i; }
        }
        rs[tid] = bs; rr[tid] = br; ri[tid] = bi;
        __syncthreads();
        for (int off = 128; off; off >>= 1) {
            if (tid < off) {
                if (rs[tid + off] > rs[tid] ||
                    (rs[tid + off] == rs[tid] && rr[tid + off] < rr[tid])) {
                    rs[tid] = rs[tid + off]; rr[tid] = rr[tid + off]; ri[tid] = ri[tid + off];
                }
            }
            __syncthreads();
        }
        if (tid == 0) {
            float s = rs[0]; int idx = ri[0];
            if (idx < 0 || !(s > NEGINF)) {
                out[it] = 0.0f;
                out[DETS + it * 4 + 0] = 0.0f;
                out[DETS + it * 4 + 1] = 0.0f;
                out[DETS + it * 4 + 2] = 0.0f;
                out[DETS + it * 4 + 3] = 0.0f;
                out[DETS * 5 + it] = 0.0f;
            } else {
                out[it] = s;
                out[DETS + it * 4 + 0] = pool_box[(size_t)idx * 4 + 0];
                out[DETS + it * 4 + 1] = pool_box[(size_t)idx * 4 + 1];
                out[DETS + it * 4 + 2] = pool_box[(size_t)idx * 4 + 2];
                out[DETS + it * 4 + 3] = pool_box[(size_t)idx * 4 + 3];
                out[DETS * 5 + it] = (float)(rr[0] / 1024 + 1);  // label
                if (use_lds) ls[idx] = NEGINF; else pool_s[idx] = NEGINF;
            }
        }
        __syncthreads();
    }
}

extern "C" void kernel_launch(void* const* d_in, const int* in_sizes, int n_in,
                              void* d_out, int out_size, void* d_ws, size_t ws_size,
                              hipStream_t stream) {
    const float* logits = (const float*)d_in[0];
    const float* boxreg = (const float*)d_in[1];
    const float* refb   = (const float*)d_in[2];
    const int*   Hp     = (const int*)d_in[3];
    const int*   Wp     = (const int*)d_in[4];
    float* out = (float*)d_out;

    int N = in_sizes[2] / 4;            // 1024
    int C = in_sizes[0] / N;            // 81
    int K = C - 1;                      // 80

    // workspace layout tiers (fit to ws_size)
    int slots = 1024, poolcap = 81920;
    auto need = [&](int sl, int pc) -> size_t {
        return 512 + (size_t)K * sl * 8 + (size_t)pc * 24;
    };
    if (need(slots, poolcap) > ws_size) { slots = 256; poolcap = 16384; }
    if (need(slots, poolcap) > ws_size) { slots = 64;  poolcap = 2048;  }

    char* w = (char*)d_ws;
    int* cnt      = (int*)w;                 // K ints
    int* pool_cnt = cnt + K;                 // 1 int
    float* cand_s    = (float*)(w + 512);
    int*   cand_n    = (int*)(w + 512 + (size_t)K * slots * 4);
    float* pool_s    = (float*)(w + 512 + (size_t)K * slots * 8);
    int*   pool_rank = (int*)(w + 512 + (size_t)K * slots * 8 + (size_t)poolcap * 4);
    float* pool_box  = (float*)(w + 512 + (size_t)K * slots * 8 + (size_t)poolcap * 8);

    hipLaunchKernelGGL(k0_init, dim3(1), dim3(128), 0, stream, cnt, pool_cnt, K);
    hipLaunchKernelGGL(k1_softmax, dim3(N), dim3(64), 0, stream,
                       logits, C, cnt, cand_s, cand_n, slots);
    hipLaunchKernelGGL(k2_sort_nms, dim3(K), dim3(256), 0, stream,
                       boxreg, refb, Hp, Wp, C, cnt, cand_s, cand_n, slots,
                       pool_cnt, pool_s, pool_rank, pool_box, poolcap);
    hipLaunchKernelGGL(k3_topk, dim3(1), dim3(256), 0, stream,
                       pool_cnt, pool_s, pool_rank, pool_box, poolcap, out);
}

// Round 2
// 232.392 us; speedup vs baseline: 1.9875x; 1.9875x over previous
//
#include <hip/hip_runtime.h>

#define NEGINF (-__builtin_inff())
#define DETS 100
#define CLASS_CAP 100          // max pool entries per class (superset of its top-100 contribution)
#define POOL_CAP 8192          // >= 80 * CLASS_CAP
#define SORT_N 1024

__device__ __forceinline__ bool precedes(float si, int ni, float sj, int nj) {
    // total order: score descending, then original index ascending
    return (si > sj) || (si == sj && ni < nj);
}

__device__ __forceinline__ float4 decode_box(const float* __restrict__ br4,
                                             float rx1, float ry1, float rx2, float ry2,
                                             float wmax, float hmax) {
    const float CLIP = 4.135166556742356f;  // log(1000/16)
    float w  = rx2 - rx1 + 1.0f;
    float h  = ry2 - ry1 + 1.0f;
    float cx = rx1 + 0.5f * w;
    float cy = ry1 + 0.5f * h;
    float dx = br4[0] / 10.0f;
    float dy = br4[1] / 10.0f;
    float dw = fminf(br4[2] / 5.0f, CLIP);
    float dh = fminf(br4[3] / 5.0f, CLIP);
    float pcx = dx * w + cx;
    float pcy = dy * h + cy;
    float pw  = expf(dw) * w;
    float ph  = expf(dh) * h;
    float4 b;
    b.x = fminf(fmaxf(pcx - 0.5f * pw, 0.0f), wmax);
    b.y = fminf(fmaxf(pcy - 0.5f * ph, 0.0f), hmax);
    b.z = fminf(fmaxf(pcx + 0.5f * pw - 1.0f, 0.0f), wmax);
    b.w = fminf(fmaxf(pcy + 0.5f * ph - 1.0f, 0.0f), hmax);
    return b;
}

// ---------------- k0: zero counters ----------------
__global__ void k0_init(int* cnt, int* pool_cnt, int K) {
    int t = threadIdx.x;
    if (t < K) cnt[t] = 0;
    if (t == K) *pool_cnt = 0;
}

// ---------------- k1: softmax + threshold + append candidates ----------------
__global__ void k1_softmax(const float* __restrict__ logits, int C,
                           int* __restrict__ cnt,
                           float* __restrict__ cand_s, int* __restrict__ cand_n,
                           int slots) {
    int n = blockIdx.x;
    int lane = threadIdx.x;  // 64 threads = 1 wave
    const float* row = logits + (size_t)n * C;

    float l0 = (lane < C) ? row[lane] : NEGINF;
    float l1 = (lane + 64 < C) ? row[lane + 64] : NEGINF;

    float m = fmaxf(l0, l1);
    #pragma unroll
    for (int o = 32; o; o >>= 1) m = fmaxf(m, __shfl_xor(m, o));

    float e0 = (lane < C) ? expf(l0 - m) : 0.0f;
    float e1 = (lane + 64 < C) ? expf(l1 - m) : 0.0f;
    float s = e0 + e1;
    #pragma unroll
    for (int o = 32; o; o >>= 1) s += __shfl_xor(s, o);

    if (lane >= 1 && lane < C) {
        float p = e0 / s;
        if (p > 0.05f) {
            int k = lane - 1;
            int slot = atomicAdd(&cnt[k], 1);
            if (slot < slots) {
                cand_s[(size_t)k * slots + slot] = p;
                cand_n[(size_t)k * slots + slot] = n;
            }
        }
    }
    if (lane + 64 < C) {
        float p = e1 / s;
        if (p > 0.05f) {
            int k = lane + 64 - 1;
            int slot = atomicAdd(&cnt[k], 1);
            if (slot < slots) {
                cand_s[(size_t)k * slots + slot] = p;
                cand_n[(size_t)k * slots + slot] = n;
            }
        }
    }
}

// ---------------- k2: per-class decode + sort + greedy NMS + capped pool append ----------------
__global__ void k2_sort_nms(const float* __restrict__ boxreg, const float* __restrict__ refb,
                            const int* __restrict__ Hp, const int* __restrict__ Wp, int C,
                            const int* __restrict__ cnt,
                            const float* __restrict__ cand_s, const int* __restrict__ cand_n,
                            int slots,
                            int* __restrict__ pool_cnt, float* __restrict__ pool_s,
                            int* __restrict__ pool_rank, float* __restrict__ pool_box) {
    __shared__ float s_l[SORT_N];
    __shared__ int   n_l[SORT_N];
    __shared__ float4 b_l[SORT_N];
    __shared__ unsigned char keepf[SORT_N];
    __shared__ int   tcnt[256];
    __shared__ int   s_base;

    int k = blockIdx.x;      // 0..K-1
    int c = k + 1;           // class id
    int tid = threadIdx.x;   // 256 threads
    int M = cnt[k];
    if (M > slots) M = slots;
    if (M == 0) return;

    float wmax = (float)(*Wp) - 1.0f;
    float hmax = (float)(*Hp) - 1.0f;

    // load + decode
    for (int i = tid; i < SORT_N; i += 256) {
        if (i < M) {
            float sc = cand_s[(size_t)k * slots + i];
            int n = cand_n[(size_t)k * slots + i];
            const float* rb = refb + (size_t)n * 4;
            const float* br = boxreg + (size_t)n * (4 * C) + (size_t)c * 4;
            b_l[i] = decode_box(br, rb[0], rb[1], rb[2], rb[3], wmax, hmax);
            s_l[i] = sc;
            n_l[i] = n;
        } else {
            s_l[i] = NEGINF;
            n_l[i] = 0x7fffffff;
            b_l[i] = make_float4(0.f, 0.f, 0.f, 0.f);
        }
    }

    // bitonic sort: descending by score, ties by original index ascending
    for (int size = 2; size <= SORT_N; size <<= 1) {
        for (int stride = size >> 1; stride > 0; stride >>= 1) {
            __syncthreads();
            for (int i = tid; i < SORT_N; i += 256) {
                int j = i ^ stride;
                if (j > i) {
                    bool up = ((i & size) == 0);
                    float si = s_l[i], sj = s_l[j];
                    int ni = n_l[i], nj = n_l[j];
                    bool do_swap = up ? precedes(sj, nj, si, ni)
                                      : precedes(si, ni, sj, nj);
                    if (do_swap) {
                        s_l[i] = sj; s_l[j] = si;
                        n_l[i] = nj; n_l[j] = ni;
                        float4 t = b_l[i]; b_l[i] = b_l[j]; b_l[j] = t;
                    }
                }
            }
        }
    }
    __syncthreads();

    for (int i = tid; i < SORT_N; i += 256) keepf[i] = (i < M) ? 1 : 0;

    // greedy NMS (IoU with +1 convention, strict > 0.5)
    for (int i = 0; i < M; ++i) {
        __syncthreads();
        if (!keepf[i]) continue;  // uniform read of same LDS byte
        float4 bi = b_l[i];
        float ai = (bi.z - bi.x + 1.0f) * (bi.w - bi.y + 1.0f);
        for (int j = i + 1 + tid; j < M; j += 256) {
            if (!keepf[j]) continue;
            float4 bj = b_l[j];
            float iw = fminf(bi.z, bj.z) - fmaxf(bi.x, bj.x) + 1.0f;
            if (iw <= 0.0f) continue;
            float ih = fminf(bi.w, bj.w) - fmaxf(bi.y, bj.y) + 1.0f;
            if (ih <= 0.0f) continue;
            float inter = iw * ih;
            float aj = (bj.z - bj.x + 1.0f) * (bj.w - bj.y + 1.0f);
            float iou = inter / (ai + aj - inter);
            if (iou > 0.5f) keepf[j] = 0;
        }
    }
    __syncthreads();

    // survivor ranks via blocked prefix scan (preserves sorted order), cap at CLASS_CAP
    const int SEG = SORT_N / 256;  // 4
    int c0 = 0;
    #pragma unroll
    for (int u = 0; u < SEG; ++u) {
        int i = tid * SEG + u;
        if (keepf[i]) c0++;
    }
    tcnt[tid] = c0;
    __syncthreads();
    for (int off = 1; off < 256; off <<= 1) {
        int v = (tid >= off) ? tcnt[tid - off] : 0;
        __syncthreads();
        tcnt[tid] += v;
        __syncthreads();
    }
    int excl = tcnt[tid] - c0;
    int Stot = tcnt[255];
    int A = (Stot < CLASS_CAP) ? Stot : CLASS_CAP;
    if (tid == 0) s_base = atomicAdd(pool_cnt, A);
    __syncthreads();
    int base = s_base;

    int r = excl;
    #pragma unroll
    for (int u = 0; u < SEG; ++u) {
        int i = tid * SEG + u;
        if (keepf[i]) {
            if (r < CLASS_CAP) {
                int p = base + r;
                pool_s[p] = s_l[i];
                pool_rank[p] = k * 1024 + i;  // reference flat index
                float4 b = b_l[i];
                pool_box[(size_t)p * 4 + 0] = b.x;
                pool_box[(size_t)p * 4 + 1] = b.y;
                pool_box[(size_t)p * 4 + 2] = b.z;
                pool_box[(size_t)p * 4 + 3] = b.w;
            }
            r++;
        }
    }
}

// ---------------- k3: bitonic sort pool by (score desc, rank asc), write top-100 ----------------
__global__ void k3_sort_out(const int* __restrict__ pool_cnt, const float* __restrict__ pool_s,
                            const int* __restrict__ pool_rank, const float* __restrict__ pool_box,
                            float* __restrict__ out) {
    __shared__ unsigned long long key[POOL_CAP];
    __shared__ int idx[POOL_CAP];

    int tid = threadIdx.x;  // 1024 threads
    int P = *pool_cnt;
    if (P > POOL_CAP) P = POOL_CAP;
    int P2 = 128;
    while (P2 < P) P2 <<= 1;

    for (int i = tid; i < P2; i += 1024) {
        if (i < P) {
            unsigned int sb = __float_as_uint(pool_s[i]);     // scores in (0.05,1] -> monotone bits
            unsigned int rk = ~(unsigned int)pool_rank[i];    // smaller rank -> larger key
            key[i] = ((unsigned long long)sb << 32) | rk;
            idx[i] = i;
        } else {
            key[i] = 0ull;
            idx[i] = -1;
        }
    }

    // bitonic sort descending
    for (int size = 2; size <= P2; size <<= 1) {
        for (int stride = size >> 1; stride > 0; stride >>= 1) {
            __syncthreads();
            for (int i = tid; i < P2; i += 1024) {
                int j = i ^ stride;
                if (j > i) {
                    bool desc = ((i & size) == 0);
                    unsigned long long ki = key[i], kj = key[j];
                    bool do_swap = desc ? (kj > ki) : (ki > kj);
                    if (do_swap) {
                        key[i] = kj; key[j] = ki;
                        int t = idx[i]; idx[i] = idx[j]; idx[j] = t;
                    }
                }
            }
        }
    }
    __syncthreads();

    if (tid < DETS) {
        int it = tid;
        int id = idx[it];
        if (id < 0) {
            out[it] = 0.0f;
            out[DETS + it * 4 + 0] = 0.0f;
            out[DETS + it * 4 + 1] = 0.0f;
            out[DETS + it * 4 + 2] = 0.0f;
            out[DETS + it * 4 + 3] = 0.0f;
            out[DETS * 5 + it] = 0.0f;
        } else {
            unsigned long long kk = key[it];
            float s = __uint_as_float((unsigned int)(kk >> 32));
            unsigned int rank = ~(unsigned int)(kk & 0xFFFFFFFFull);
            out[it] = s;
            out[DETS + it * 4 + 0] = pool_box[(size_t)id * 4 + 0];
            out[DETS + it * 4 + 1] = pool_box[(size_t)id * 4 + 1];
            out[DETS + it * 4 + 2] = pool_box[(size_t)id * 4 + 2];
            out[DETS + it * 4 + 3] = pool_box[(size_t)id * 4 + 3];
            out[DETS * 5 + it] = (float)(rank / 1024u + 1u);
        }
    }
}

extern "C" void kernel_launch(void* const* d_in, const int* in_sizes, int n_in,
                              void* d_out, int out_size, void* d_ws, size_t ws_size,
                              hipStream_t stream) {
    const float* logits = (const float*)d_in[0];
    const float* boxreg = (const float*)d_in[1];
    const float* refb   = (const float*)d_in[2];
    const int*   Hp     = (const int*)d_in[3];
    const int*   Wp     = (const int*)d_in[4];
    float* out = (float*)d_out;

    int N = in_sizes[2] / 4;            // 1024
    int C = in_sizes[0] / N;            // 81
    int K = C - 1;                      // 80

    // workspace layout tiers (fit to ws_size)
    int slots = 1024;
    auto need = [&](int sl) -> size_t {
        return 512 + (size_t)K * sl * 8 + (size_t)POOL_CAP * 24;
    };
    if (need(slots) > ws_size) slots = 256;
    if (need(slots) > ws_size) slots = 64;

    char* w = (char*)d_ws;
    int* cnt      = (int*)w;                 // K ints
    int* pool_cnt = cnt + K;                 // 1 int
    float* cand_s    = (float*)(w + 512);
    int*   cand_n    = (int*)(w + 512 + (size_t)K * slots * 4);
    float* pool_s    = (float*)(w + 512 + (size_t)K * slots * 8);
    int*   pool_rank = (int*)(w + 512 + (size_t)K * slots * 8 + (size_t)POOL_CAP * 4);
    float* pool_box  = (float*)(w + 512 + (size_t)K * slots * 8 + (size_t)POOL_CAP * 8);

    hipLaunchKernelGGL(k0_init, dim3(1), dim3(128), 0, stream, cnt, pool_cnt, K);
    hipLaunchKernelGGL(k1_softmax, dim3(N), dim3(64), 0, stream,
                       logits, C, cnt, cand_s, cand_n, slots);
    hipLaunchKernelGGL(k2_sort_nms, dim3(K), dim3(256), 0, stream,
                       boxreg, refb, Hp, Wp, C, cnt, cand_s, cand_n, slots,
                       pool_cnt, pool_s, pool_rank, pool_box);
    hipLaunchKernelGGL(k3_sort_out, dim3(1), dim3(1024), 0, stream,
                       pool_cnt, pool_s, pool_rank, pool_box, out);
}

// Round 3
// 74.506 us; speedup vs baseline: 6.1993x; 3.1191x over previous
//
#include <hip/hip_runtime.h>

#define NEGINF (-__builtin_inff())
#define DETS 100
#define CLASS_CAP 100          // max pool entries per class (superset of its top-100 contribution)
#define POOL_CAP 8192          // >= 80 * CLASS_CAP
#define CAND_MAX 1024          // max candidates per class
#define SEL_CAP 2048           // fast-path selection capacity in k3

typedef unsigned long long u64;
typedef unsigned int u32;

__device__ __forceinline__ float4 decode_box(const float* __restrict__ br4,
                                             float rx1, float ry1, float rx2, float ry2,
                                             float wmax, float hmax) {
    const float CLIP = 4.135166556742356f;  // log(1000/16)
    float w  = rx2 - rx1 + 1.0f;
    float h  = ry2 - ry1 + 1.0f;
    float cx = rx1 + 0.5f * w;
    float cy = ry1 + 0.5f * h;
    float dx = br4[0] / 10.0f;
    float dy = br4[1] / 10.0f;
    float dw = fminf(br4[2] / 5.0f, CLIP);
    float dh = fminf(br4[3] / 5.0f, CLIP);
    float pcx = dx * w + cx;
    float pcy = dy * h + cy;
    float pw  = expf(dw) * w;
    float ph  = expf(dh) * h;
    float4 b;
    b.x = fminf(fmaxf(pcx - 0.5f * pw, 0.0f), wmax);
    b.y = fminf(fmaxf(pcy - 0.5f * ph, 0.0f), hmax);
    b.z = fminf(fmaxf(pcx + 0.5f * pw - 1.0f, 0.0f), wmax);
    b.w = fminf(fmaxf(pcy + 0.5f * ph - 1.0f, 0.0f), hmax);
    return b;
}

// ---------------- k0: zero counters ----------------
__global__ void k0_init(int* cnt, int* pool_cnt, int K) {
    int t = threadIdx.x;
    if (t < K) cnt[t] = 0;
    if (t == K) *pool_cnt = 0;
}

// ---------------- k1: softmax + threshold + append candidates ----------------
__global__ void k1_softmax(const float* __restrict__ logits, int C,
                           int* __restrict__ cnt,
                           float* __restrict__ cand_s, int* __restrict__ cand_n,
                           int slots) {
    int n = blockIdx.x;
    int lane = threadIdx.x;  // 64 threads = 1 wave
    const float* row = logits + (size_t)n * C;

    float l0 = (lane < C) ? row[lane] : NEGINF;
    float l1 = (lane + 64 < C) ? row[lane + 64] : NEGINF;

    float m = fmaxf(l0, l1);
    #pragma unroll
    for (int o = 32; o; o >>= 1) m = fmaxf(m, __shfl_xor(m, o));

    float e0 = (lane < C) ? expf(l0 - m) : 0.0f;
    float e1 = (lane + 64 < C) ? expf(l1 - m) : 0.0f;
    float s = e0 + e1;
    #pragma unroll
    for (int o = 32; o; o >>= 1) s += __shfl_xor(s, o);

    if (lane >= 1 && lane < C) {
        float p = e0 / s;
        if (p > 0.05f) {
            int k = lane - 1;
            int slot = atomicAdd(&cnt[k], 1);
            if (slot < slots) {
                cand_s[(size_t)k * slots + slot] = p;
                cand_n[(size_t)k * slots + slot] = n;
            }
        }
    }
    if (lane + 64 < C) {
        float p = e1 / s;
        if (p > 0.05f) {
            int k = lane + 64 - 1;
            int slot = atomicAdd(&cnt[k], 1);
            if (slot < slots) {
                cand_s[(size_t)k * slots + slot] = p;
                cand_n[(size_t)k * slots + slot] = n;
            }
        }
    }
}

// ---------------- k2: per-class key-sort + decode + wave-NMS + pool append ----------------
__global__ void k2_sort_nms(const float* __restrict__ boxreg, const float* __restrict__ refb,
                            const int* __restrict__ Hp, const int* __restrict__ Wp, int C, int N,
                            const int* __restrict__ cnt,
                            const float* __restrict__ cand_s, const int* __restrict__ cand_n,
                            int slots,
                            int* __restrict__ pool_cnt, float* __restrict__ pool_s,
                            int* __restrict__ pool_rank, float* __restrict__ pool_box) {
    __shared__ u64 key[CAND_MAX];
    __shared__ float4 b_l[CAND_MAX];
    __shared__ unsigned char keepf_s[CAND_MAX];
    volatile unsigned char* keepf = keepf_s;

    int k = blockIdx.x;      // 0..K-1
    int c = k + 1;           // class id
    int tid = threadIdx.x;   // 256 threads
    int M = cnt[k];
    if (M > slots) M = slots;
    if (M == 0) return;

    int P2 = 64;
    while (P2 < M) P2 <<= 1;

    // load keys: (score_bits << 32) | ~n  -> descending sort == (score desc, n asc)
    for (int i = tid; i < P2; i += 256) {
        if (i < M) {
            u32 sb = __float_as_uint(cand_s[(size_t)k * slots + i]);  // scores > 0 -> monotone bits
            u32 nv = ~(u32)cand_n[(size_t)k * slots + i];
            key[i] = ((u64)sb << 32) | nv;
        } else {
            key[i] = 0ull;
        }
    }

    // bitonic sort descending (keys only)
    for (int size = 2; size <= P2; size <<= 1) {
        for (int stride = size >> 1; stride > 0; stride >>= 1) {
            __syncthreads();
            for (int i = tid; i < P2; i += 256) {
                int j = i ^ stride;
                if (j > i) {
                    bool desc = ((i & size) == 0);
                    u64 ki = key[i], kj = key[j];
                    bool do_swap = desc ? (kj > ki) : (ki > kj);
                    if (do_swap) { key[i] = kj; key[j] = ki; }
                }
            }
        }
    }
    __syncthreads();

    // decode boxes in sorted order
    float wmax = (float)(*Wp) - 1.0f;
    float hmax = (float)(*Hp) - 1.0f;
    for (int i = tid; i < M; i += 256) {
        int n = (int)(~(u32)key[i]);
        const float* rb = refb + (size_t)n * 4;
        const float* br = boxreg + (size_t)n * (4 * C) + (size_t)c * 4;
        b_l[i] = decode_box(br, rb[0], rb[1], rb[2], rb[3], wmax, hmax);
        keepf_s[i] = 1;
    }
    __syncthreads();

    // greedy NMS, wave 0 only, barrier-free (wave-synchronous, volatile LDS flags)
    if (tid < 64) {
        int lane = tid;
        for (int i = 0; i < M - 1; ++i) {
            if (!keepf[i]) continue;          // uniform broadcast read
            float4 bi = b_l[i];
            float ai = (bi.z - bi.x + 1.0f) * (bi.w - bi.y + 1.0f);
            for (int j = i + 1 + lane; j < M; j += 64) {
                if (!keepf[j]) continue;
                float4 bj = b_l[j];
                float iw = fminf(bi.z, bj.z) - fmaxf(bi.x, bj.x) + 1.0f;
                if (iw <= 0.0f) continue;
                float ih = fminf(bi.w, bj.w) - fmaxf(bi.y, bj.y) + 1.0f;
                if (ih <= 0.0f) continue;
                float inter = iw * ih;
                float aj = (bj.z - bj.x + 1.0f) * (bj.w - bj.y + 1.0f);
                float iou = inter / (ai + aj - inter);
                if (iou > 0.5f) keepf[j] = 0;
            }
        }

        // ballot compaction + pool append (wave 0)
        int nch = (M + 63) >> 6;
        int total = 0;
        for (int ch = 0; ch < nch; ++ch) {
            int j = ch * 64 + lane;
            bool kp = (j < M) && keepf[j];
            u64 mask = __ballot(kp);
            total += __popcll(mask);
        }
        int A = (total < CLASS_CAP) ? total : CLASS_CAP;
        int base = 0;
        if (lane == 0) base = atomicAdd(pool_cnt, A);
        base = __shfl(base, 0);

        int r = 0;
        for (int ch = 0; ch < nch; ++ch) {
            int j = ch * 64 + lane;
            bool kp = (j < M) && keepf[j];
            u64 mask = __ballot(kp);
            if (kp) {
                int rr = r + __popcll(mask & ((1ull << lane) - 1ull));
                if (rr < CLASS_CAP) {
                    int p = base + rr;
                    pool_s[p] = __uint_as_float((u32)(key[j] >> 32));
                    pool_rank[p] = k * N + j;     // reference flat index
                    float4 b = b_l[j];
                    pool_box[(size_t)p * 4 + 0] = b.x;
                    pool_box[(size_t)p * 4 + 1] = b.y;
                    pool_box[(size_t)p * 4 + 2] = b.z;
                    pool_box[(size_t)p * 4 + 3] = b.w;
                }
            }
            r += __popcll(mask);
        }
    }
}

// ---------------- k3: histogram select + small sort + write top-100 ----------------
__global__ void k3_select(const int* __restrict__ pool_cnt, const float* __restrict__ pool_s,
                          const int* __restrict__ pool_rank, const float* __restrict__ pool_box,
                          int N, float* __restrict__ out) {
    __shared__ u64 key[POOL_CAP];
    __shared__ int idx[POOL_CAP];
    __shared__ int hist[256];
    __shared__ int cum[256];
    __shared__ int s_B;
    __shared__ int s_cc;

    const int BOFF = (int)(0x3D4CCCCDu >> 18);  // bucket of 0.05f
    int tid = threadIdx.x;  // 256 threads
    int P = *pool_cnt;
    if (P > POOL_CAP) P = POOL_CAP;

    if (P == 0) {
        if (tid < DETS) {
            out[tid] = 0.0f;
            out[DETS + tid * 4 + 0] = 0.0f;
            out[DETS + tid * 4 + 1] = 0.0f;
            out[DETS + tid * 4 + 2] = 0.0f;
            out[DETS + tid * 4 + 3] = 0.0f;
            out[DETS * 5 + tid] = 0.0f;
        }
        return;
    }

    hist[tid] = 0;
    if (tid == 0) { s_B = 0; s_cc = 0; }
    __syncthreads();

    // 256-bucket monotone histogram of score bits
    for (int i = tid; i < P; i += 256) {
        u32 sb = __float_as_uint(pool_s[i]);
        int b = (int)(sb >> 18) - BOFF;
        b = (b < 0) ? 0 : (b > 255 ? 255 : b);
        atomicAdd(&hist[b], 1);
    }
    __syncthreads();

    // inclusive suffix scan: cum[b] = sum_{b' >= b} hist[b']
    cum[tid] = hist[tid];
    __syncthreads();
    for (int off = 1; off < 256; off <<= 1) {
        int v = (tid + off < 256) ? cum[tid + off] : 0;
        __syncthreads();
        cum[tid] += v;
        __syncthreads();
    }

    // find B = max b with cum[b] >= target
    int target = (P < DETS) ? P : DETS;
    if (cum[tid] >= target && (tid == 255 || cum[tid + 1] < target)) s_B = tid;
    __syncthreads();
    int B = s_B;
    int CC = cum[B];

    int S;
    if (CC <= SEL_CAP) {
        // fast path: compact only buckets >= B (superset of top-100 by score)
        for (int i = tid; i < P; i += 256) {
            u32 sb = __float_as_uint(pool_s[i]);
            int b = (int)(sb >> 18) - BOFF;
            b = (b < 0) ? 0 : (b > 255 ? 255 : b);
            if (b >= B) {
                int pos = atomicAdd(&s_cc, 1);
                key[pos] = ((u64)sb << 32) | (u32)(~(u32)pool_rank[i]);
                idx[pos] = i;
            }
        }
        S = CC;
    } else {
        // fallback (massive ties): load everything
        for (int i = tid; i < P; i += 256) {
            u32 sb = __float_as_uint(pool_s[i]);
            key[i] = ((u64)sb << 32) | (u32)(~(u32)pool_rank[i]);
            idx[i] = i;
        }
        S = P;
    }
    __syncthreads();

    int S2 = 128;
    while (S2 < S) S2 <<= 1;
    for (int i = tid; i < S2; i += 256) {
        if (i >= S) { key[i] = 0ull; idx[i] = -1; }
    }

    // bitonic sort descending by key = (score desc, rank asc)
    for (int size = 2; size <= S2; size <<= 1) {
        for (int stride = size >> 1; stride > 0; stride >>= 1) {
            __syncthreads();
            for (int i = tid; i < S2; i += 256) {
                int j = i ^ stride;
                if (j > i) {
                    bool desc = ((i & size) == 0);
                    u64 ki = key[i], kj = key[j];
                    bool do_swap = desc ? (kj > ki) : (ki > kj);
                    if (do_swap) {
                        key[i] = kj; key[j] = ki;
                        int t = idx[i]; idx[i] = idx[j]; idx[j] = t;
                    }
                }
            }
        }
    }
    __syncthreads();

    if (tid < DETS) {
        int it = tid;
        int id = (it < S) ? idx[it] : -1;
        if (id < 0) {
            out[it] = 0.0f;
            out[DETS + it * 4 + 0] = 0.0f;
            out[DETS + it * 4 + 1] = 0.0f;
            out[DETS + it * 4 + 2] = 0.0f;
            out[DETS + it * 4 + 3] = 0.0f;
            out[DETS * 5 + it] = 0.0f;
        } else {
            u64 kk = key[it];
            float s = __uint_as_float((u32)(kk >> 32));
            u32 rank = ~(u32)(kk & 0xFFFFFFFFull);
            out[it] = s;
            out[DETS + it * 4 + 0] = pool_box[(size_t)id * 4 + 0];
            out[DETS + it * 4 + 1] = pool_box[(size_t)id * 4 + 1];
            out[DETS + it * 4 + 2] = pool_box[(size_t)id * 4 + 2];
            out[DETS + it * 4 + 3] = pool_box[(size_t)id * 4 + 3];
            out[DETS * 5 + it] = (float)(rank / (u32)N + 1u);
        }
    }
}

extern "C" void kernel_launch(void* const* d_in, const int* in_sizes, int n_in,
                              void* d_out, int out_size, void* d_ws, size_t ws_size,
                              hipStream_t stream) {
    const float* logits = (const float*)d_in[0];
    const float* boxreg = (const float*)d_in[1];
    const float* refb   = (const float*)d_in[2];
    const int*   Hp     = (const int*)d_in[3];
    const int*   Wp     = (const int*)d_in[4];
    float* out = (float*)d_out;

    int N = in_sizes[2] / 4;            // 1024
    int C = in_sizes[0] / N;            // 81
    int K = C - 1;                      // 80

    // workspace layout tiers (fit to ws_size)
    int slots = 1024;
    auto need = [&](int sl) -> size_t {
        return 512 + (size_t)K * sl * 8 + (size_t)POOL_CAP * 24;
    };
    if (need(slots) > ws_size) slots = 256;
    if (need(slots) > ws_size) slots = 64;

    char* w = (char*)d_ws;
    int* cnt      = (int*)w;                 // K ints
    int* pool_cnt = cnt + K;                 // 1 int
    float* cand_s    = (float*)(w + 512);
    int*   cand_n    = (int*)(w + 512 + (size_t)K * slots * 4);
    float* pool_s    = (float*)(w + 512 + (size_t)K * slots * 8);
    int*   pool_rank = (int*)(w + 512 + (size_t)K * slots * 8 + (size_t)POOL_CAP * 4);
    float* pool_box  = (float*)(w + 512 + (size_t)K * slots * 8 + (size_t)POOL_CAP * 8);

    hipLaunchKernelGGL(k0_init, dim3(1), dim3(128), 0, stream, cnt, pool_cnt, K);
    hipLaunchKernelGGL(k1_softmax, dim3(N), dim3(64), 0, stream,
                       logits, C, cnt, cand_s, cand_n, slots);
    hipLaunchKernelGGL(k2_sort_nms, dim3(K), dim3(256), 0, stream,
                       boxreg, refb, Hp, Wp, C, N, cnt, cand_s, cand_n, slots,
                       pool_cnt, pool_s, pool_rank, pool_box);
    hipLaunchKernelGGL(k3_select, dim3(1), dim3(256), 0, stream,
                       pool_cnt, pool_s, pool_rank, pool_box, N, out);
}